// Round 11
// baseline (119.977 us; speedup 1.0000x reference)
//
#include <hip/hip_runtime.h>

typedef __attribute__((ext_vector_type(8))) short s16x8;
typedef __attribute__((ext_vector_type(4))) float f32x4;

__device__ inline float bf2f(ushort u) {
    union { unsigned int i; float f; } v; v.i = ((unsigned)u) << 16; return v.f;
}
__device__ inline float u2f(unsigned u) {
    union { unsigned int i; float f; } v; v.i = u; return v.f;
}
__device__ inline ushort f2bf(float f) {
    union { float f; unsigned int i; } v; v.f = f;
    unsigned r = v.i + 0x7FFFu + ((v.i >> 16) & 1u);
    return (ushort)(r >> 16);
}
__device__ inline unsigned cvt_pk(float lo, float hi) {
    unsigned d;
    asm("v_cvt_pk_bf16_f32 %0, %1, %2" : "=v"(d) : "v"(lo), "v"(hi));
    return d;
}
// fast silu: x * rcp(1 + 2^(-x*log2e)) — 5 VALU ops, correct at +-inf
__device__ inline float silu_f(float x) {
    float e;
    asm("v_exp_f32 %0, %1" : "=v"(e) : "v"(x * -1.44269504f));
    float d = 1.f + e, r;
    asm("v_rcp_f32 %0, %1" : "=v"(r) : "v"(d));
    return x * r;
}

// K1 merged: blocks [0, N/32) do node_up (32 nodes/block); rest do prep+counts.
// wimg ushort layout:
//   [0,4096)       W1t  (64m x 64k, k<8 real else 0), A-side swizzle
//   [4096,8192)    W2t  (64 x 64)
//   [8192,12288)   W3t  (64 x 64)
//   [12288,20480)  W4t  (128m x 64k)
//   [20480,29696)  wl_img: (l*64+col)*72 + c  = W_lin[l][c][col]
//   [29696,38912)  wp_img: (l*64+col)*72 + c  = W_p{l}[c][col]
//   [38912,79872)  wskb: W_skip bf16 linear (c*10+a)*64+k
__global__ __launch_bounds__(256) void prep_up_kernel(
    const float* __restrict__ nf, const float* __restrict__ W_up,
    ushort* __restrict__ x_ws,
    const float* __restrict__ W1, const float* __restrict__ W2,
    const float* __restrict__ W3, const float* __restrict__ W4,
    const float* __restrict__ W_lin, const float* __restrict__ Wp0,
    const float* __restrict__ Wp1, const float* __restrict__ W_skip,
    ushort* __restrict__ wimg, int* __restrict__ counts, int N) {
    __shared__ float sW[64 * 64];
    __shared__ float sNf[32][64];
    int tid = threadIdx.x;
    int nub = N / 32;
    if ((int)blockIdx.x < nub) {
        size_t n0 = (size_t)blockIdx.x * 32;
        for (int i = tid; i < 4096; i += 256) sW[i] = W_up[i];
        for (int i = tid; i < 2048; i += 256) {
            int r = i >> 6, c = i & 63;
            sNf[r][c] = nf[(n0 + r) * 64 + c];
        }
        __syncthreads();
        int r = tid >> 3, k0 = (tid & 7) * 8;
        float acc[8] = {0, 0, 0, 0, 0, 0, 0, 0};
        #pragma unroll 4
        for (int c = 0; c < 64; ++c) {
            float v = sNf[r][c];
            const float* wr = &sW[c * 64 + k0];
            #pragma unroll
            for (int j = 0; j < 8; ++j) acc[j] += v * wr[j];
        }
        uint4 val;
        val.x = cvt_pk(acc[0], acc[1]);
        val.y = cvt_pk(acc[2], acc[3]);
        val.z = cvt_pk(acc[4], acc[5]);
        val.w = cvt_pk(acc[6], acc[7]);
        *(uint4*)(x_ws + (n0 + r) * 64 + k0) = val;
        return;
    }
    int idx = ((int)blockIdx.x - nub) * 256 + tid;
    if (idx < N) counts[idx] = 0;
    if (idx < 4096) {
        int m = idx >> 6, k = idx & 63;
        int dst = m * 64 + ((((k >> 3) ^ (m & 7))) << 3) + (k & 7);
        wimg[dst] = (k < 8) ? f2bf(W1[k * 64 + m]) : (ushort)0;
    } else if (idx < 8192) {
        int i = idx - 4096;
        int m = i >> 6, k = i & 63;
        int dst = 4096 + m * 64 + ((((k >> 3) ^ (m & 7))) << 3) + (k & 7);
        wimg[dst] = f2bf(W2[k * 64 + m]);
    } else if (idx < 12288) {
        int i = idx - 8192;
        int m = i >> 6, k = i & 63;
        int dst = 8192 + m * 64 + ((((k >> 3) ^ (m & 7))) << 3) + (k & 7);
        wimg[dst] = f2bf(W3[k * 64 + m]);
    } else if (idx < 20480) {
        int i = idx - 12288;
        int m = i >> 6, k = i & 63;  // m in 0..127
        int dst = 12288 + m * 64 + ((((k >> 3) ^ (m & 7))) << 3) + (k & 7);
        wimg[dst] = f2bf(W4[k * 256 + m]);
    } else if (idx < 29696) {
        int i = idx - 20480;
        int row = i / 72, k = i % 72;
        int l = row >> 6, col = row & 63;
        wimg[idx] = (k < 64) ? f2bf(W_lin[l * 4096 + k * 64 + col]) : (ushort)0;
    } else if (idx < 38912) {
        int i = idx - 29696;
        int row = i / 72, k = i % 72;
        int l = row >> 6, col = row & 63;
        const float* Wp = l ? Wp1 : Wp0;
        wimg[idx] = (k < 64) ? f2bf(Wp[k * 64 + col]) : (ushort)0;
    } else if (idx < 79872) {
        int i = idx - 38912;
        wimg[idx] = f2bf(W_skip[i]);
    }
}

// K2: histogram of receivers
__global__ __launch_bounds__(256) void hist_kernel(const int* __restrict__ recv,
                                                   int* __restrict__ counts, int E) {
    int e = blockIdx.x * 256 + threadIdx.x;
    if (e < E) atomicAdd(&counts[recv[e]], 1);
}

// K3: single-pass chunked exclusive scan counts -> offsets (and cursor copy)
__global__ __launch_bounds__(1024) void scan_kernel(const int* __restrict__ counts,
                                                    int* __restrict__ offsets,
                                                    int* __restrict__ cursor, int n) {
    __shared__ int wsums[16];
    int tid = threadIdx.x, lane = tid & 63, wid = tid >> 6;
    int CH = (n + 1023) >> 10;
    int base = tid * CH;
    int cnt[20];
    int tot = 0;
    if (CH <= 20) {
        #pragma unroll
        for (int j = 0; j < 20; ++j) {
            int i = base + j;
            cnt[j] = (j < CH && i < n) ? counts[i] : 0;
            tot += cnt[j];
        }
    } else {
        for (int j = 0; j < CH; ++j) {
            int i = base + j;
            if (i < n) tot += counts[i];
        }
    }
    int v = tot;
    for (int off = 1; off < 64; off <<= 1) {
        int t = __shfl_up(v, off, 64);
        if (lane >= off) v += t;
    }
    if (lane == 63) wsums[wid] = v;
    __syncthreads();
    if (tid == 0) {
        int acc = 0;
        for (int w = 0; w < 16; ++w) { int t = wsums[w]; wsums[w] = acc; acc += t; }
    }
    __syncthreads();
    int excl = wsums[wid] + v - tot;
    if (CH <= 20) {
        #pragma unroll
        for (int j = 0; j < 20; ++j) {
            int i = base + j;
            if (j < CH && i < n) {
                offsets[i] = excl; cursor[i] = excl; excl += cnt[j];
            }
        }
    } else {
        for (int j = 0; j < CH; ++j) {
            int i = base + j;
            if (i < n) { offsets[i] = excl; cursor[i] = excl; excl += counts[i]; }
        }
    }
    if (tid == 1023) offsets[n] = excl;
}

// K5 (fused): edge MLP in original edge order; tpw32 written CONTIGUOUSLY at
// row e; CSR permutation captured as csr_eid[pos]=e (4B scatter, hi==0 lanes).
__global__ __launch_bounds__(256) void edge_mlp_kernel(
    const int* __restrict__ recv, const float* __restrict__ radial,
    int* __restrict__ cursor, int* __restrict__ csr_eid,
    const ushort* __restrict__ wimg, unsigned* __restrict__ tpw32, int E) {
    __shared__ __align__(16) ushort sW4[8192];       // 16KB
    __shared__ __align__(16) ushort sB[4][1024];     // per-wave h bounce, 2KB each
    int tid = threadIdx.x, lane = tid & 63, wave = tid >> 6;
    int n = lane & 15, hi = lane >> 4;

    for (int i = tid; i < 1024; i += 256)
        ((s16x8*)sW4)[i] = ((const s16x8*)(wimg + 12288))[i];

    // preload A-side weight fragments (VGPR-resident, block-invariant)
    s16x8 w1f[4], w2f[4][2], w3f[4][2];
    #pragma unroll
    for (int mt = 0; mt < 4; ++mt) {
        int row = mt * 16 + n, r7 = row & 7;
        w1f[mt] = *(const s16x8*)(wimg + row * 64 + ((hi ^ r7) << 3));
        #pragma unroll
        for (int ks = 0; ks < 2; ++ks) {
            w2f[mt][ks] = *(const s16x8*)(wimg + 4096 + row * 64 + (((ks * 4 + hi) ^ r7) << 3));
            w3f[mt][ks] = *(const s16x8*)(wimg + 8192 + row * 64 + (((ks * 4 + hi) ^ r7) << 3));
        }
    }
    __syncthreads();

    char* myB = (char*)sB[wave];
    int n7 = n & 7;

    for (int sub = 0; sub < 2; ++sub) {
        int base = blockIdx.x * 128 + wave * 32 + sub * 16;
        if (base >= E) break;
        int e = base + n;
        bool oke = e < E;
        int eC = min(e, E - 1);

        // radial B-fragment packed in-register (k = hi*8+j; only k<8 real)
        // + CSR position claim (hi==0 lanes only; nothing downstream needs pos)
        s16x8 bR;
        #pragma unroll
        for (int j = 0; j < 8; ++j) bR[j] = 0;
        if (hi == 0) {
            float4 r0 = *(const float4*)(radial + (size_t)eC * 8);
            float4 r1 = *(const float4*)(radial + (size_t)eC * 8 + 4);
            union { s16x8 v; uint4 u; } bb;
            bb.u.x = cvt_pk(r0.x, r0.y);
            bb.u.y = cvt_pk(r0.z, r0.w);
            bb.u.z = cvt_pk(r1.x, r1.y);
            bb.u.w = cvt_pk(r1.z, r1.w);
            bR = bb.v;
            if (oke) {
                int pos = atomicAdd(&cursor[recv[e]], 1);
                csr_eid[pos] = e;
            }
        }

        f32x4 zero = {0.f, 0.f, 0.f, 0.f};
        f32x4 d[4];
        // L1 (K=32, zero-padded)
        #pragma unroll
        for (int mt = 0; mt < 4; ++mt)
            d[mt] = __builtin_amdgcn_mfma_f32_16x16x32_bf16(w1f[mt], bR, zero, 0, 0, 0);

        #pragma unroll
        for (int mt = 0; mt < 4; ++mt) {
            uint2 val = {cvt_pk(silu_f(d[mt][0]), silu_f(d[mt][1])),
                         cvt_pk(silu_f(d[mt][2]), silu_f(d[mt][3]))};
            int slot = mt * 2 + (hi >> 1);
            *(uint2*)(myB + n * 128 + ((slot ^ n7) << 4) + (hi & 1) * 8) = val;
        }
        s16x8 b0 = *(const s16x8*)(myB + n * 128 + ((hi ^ n7) << 4));
        s16x8 b1 = *(const s16x8*)(myB + n * 128 + (((4 + hi) ^ n7) << 4));

        // L2
        #pragma unroll
        for (int mt = 0; mt < 4; ++mt) {
            d[mt] = __builtin_amdgcn_mfma_f32_16x16x32_bf16(w2f[mt][0], b0, zero, 0, 0, 0);
            d[mt] = __builtin_amdgcn_mfma_f32_16x16x32_bf16(w2f[mt][1], b1, d[mt], 0, 0, 0);
        }
        #pragma unroll
        for (int mt = 0; mt < 4; ++mt) {
            uint2 val = {cvt_pk(silu_f(d[mt][0]), silu_f(d[mt][1])),
                         cvt_pk(silu_f(d[mt][2]), silu_f(d[mt][3]))};
            int slot = mt * 2 + (hi >> 1);
            *(uint2*)(myB + n * 128 + ((slot ^ n7) << 4) + (hi & 1) * 8) = val;
        }
        b0 = *(const s16x8*)(myB + n * 128 + ((hi ^ n7) << 4));
        b1 = *(const s16x8*)(myB + n * 128 + (((4 + hi) ^ n7) << 4));

        // L3
        #pragma unroll
        for (int mt = 0; mt < 4; ++mt) {
            d[mt] = __builtin_amdgcn_mfma_f32_16x16x32_bf16(w3f[mt][0], b0, zero, 0, 0, 0);
            d[mt] = __builtin_amdgcn_mfma_f32_16x16x32_bf16(w3f[mt][1], b1, d[mt], 0, 0, 0);
        }
        #pragma unroll
        for (int mt = 0; mt < 4; ++mt) {
            uint2 val = {cvt_pk(silu_f(d[mt][0]), silu_f(d[mt][1])),
                         cvt_pk(silu_f(d[mt][2]), silu_f(d[mt][3]))};
            int slot = mt * 2 + (hi >> 1);
            *(uint2*)(myB + n * 128 + ((slot ^ n7) << 4) + (hi & 1) * 8) = val;
        }
        b0 = *(const s16x8*)(myB + n * 128 + ((hi ^ n7) << 4));
        b1 = *(const s16x8*)(myB + n * 128 + (((4 + hi) ^ n7) << 4));

        // L4: 128 outputs (l=0,1); per mt-pair compute + pack + contiguous store.
        size_t rowbase = (size_t)e * 64;
        #pragma unroll
        for (int mt = 0; mt < 4; ++mt) {
            int row0 = mt * 16 + n, r70 = row0 & 7;
            int row1 = (mt + 4) * 16 + n, r71 = row1 & 7;
            s16x8 a0lo = *(const s16x8*)(sW4 + row0 * 64 + ((hi ^ r70) << 3));
            s16x8 a1lo = *(const s16x8*)(sW4 + row0 * 64 + (((4 + hi) ^ r70) << 3));
            s16x8 a0hi = *(const s16x8*)(sW4 + row1 * 64 + ((hi ^ r71) << 3));
            s16x8 a1hi = *(const s16x8*)(sW4 + row1 * 64 + (((4 + hi) ^ r71) << 3));
            f32x4 olo = __builtin_amdgcn_mfma_f32_16x16x32_bf16(a0lo, b0, zero, 0, 0, 0);
            olo = __builtin_amdgcn_mfma_f32_16x16x32_bf16(a1lo, b1, olo, 0, 0, 0);
            f32x4 ohi = __builtin_amdgcn_mfma_f32_16x16x32_bf16(a0hi, b0, zero, 0, 0, 0);
            ohi = __builtin_amdgcn_mfma_f32_16x16x32_bf16(a1hi, b1, ohi, 0, 0, 0);
            if (oke) {
                uint4 val;
                val.x = cvt_pk(olo[0], ohi[0]);
                val.y = cvt_pk(olo[1], ohi[1]);
                val.z = cvt_pk(olo[2], ohi[2]);
                val.w = cvt_pk(olo[3], ohi[3]);
                *(uint4*)(tpw32 + rowbase + mt * 16 + hi * 4) = val;
            }
        }
    }
}

// K6a: CSR aggregation with eid indirection. Wave per node, lane = channel.
// 4-edge batched loads hide L2/L3 gather latency.
__global__ __launch_bounds__(256) void agg_kernel(const float* __restrict__ angular,
                                                  const int* __restrict__ sender,
                                                  const int* __restrict__ csr_eid,
                                                  const unsigned* __restrict__ tpw32,
                                                  const int* __restrict__ offsets,
                                                  const ushort* __restrict__ x_ws,
                                                  ushort* __restrict__ agg, int N) {
    int wave = threadIdx.x >> 6, lane = threadIdx.x & 63;
    int node = blockIdx.x * 4 + wave;
    if (node >= N) return;
    int beg = offsets[node], end = offsets[node + 1];
    float a0 = 0, a1 = 0, a2 = 0, a3 = 0;
    for (int cb = beg; cb < end; cb += 64) {
        int m = min(64, end - cb);
        int ev = csr_eid[cb + min(lane, m - 1)];
        int sv = sender[ev];
        for (int e0 = 0; e0 < m; e0 += 4) {
            unsigned t[4];
            ushort x[4];
            float4 g[4];
            #pragma unroll
            for (int j = 0; j < 4; ++j) {
                int e = e0 + j;
                int ec = min(e, m - 1);
                int eidj = __shfl(ev, ec);
                t[j] = tpw32[(size_t)eidj * 64 + lane];
                x[j] = x_ws[(size_t)__shfl(sv, ec) * 64 + lane];
                if (e < m) g[j] = *(const float4*)(angular + (size_t)eidj * 16);
                else g[j] = make_float4(0.f, 0.f, 0.f, 0.f);
            }
            #pragma unroll
            for (int j = 0; j < 4; ++j) {
                float xv = bf2f(x[j]);
                float tp0 = u2f(t[j] << 16);
                float tp1 = u2f(t[j] & 0xffff0000u);
                float y0 = xv * tp0, y1 = xv * tp1;
                a0 += g[j].x * y0;
                a1 += g[j].y * y1;
                a2 += g[j].z * y1;
                a3 += g[j].w * y1;
            }
        }
    }
    size_t b = (size_t)node * 256 + lane;
    agg[b] = f2bf(a0 * 0.1f);
    agg[b + 64] = f2bf(a1 * 0.1f);
    agg[b + 128] = f2bf(a2 * 0.1f);
    agg[b + 192] = f2bf(a3 * 0.1f);
}

// K6b: per-32-node tile: feats = agg@W_lin (MFMA), scale by wn, out = f@W_p (+sc0).
__global__ __launch_bounds__(256) void node_out2_kernel(
    const float* __restrict__ nf, const float* __restrict__ one_hot,
    const ushort* __restrict__ wimg, const float* __restrict__ W_c0,
    const float* __restrict__ W_c1, const ushort* __restrict__ agg,
    float* __restrict__ out) {
    __shared__ __align__(16) ushort sWl[2 * 64 * 72];
    __shared__ __align__(16) ushort sF[4][32 * 72];
    __shared__ float sSc[32][64];
    __shared__ float sWc[2][640];
    __shared__ int sElem[32];
    int tid = threadIdx.x;
    int n0 = blockIdx.x * 32;
    int lane = tid & 63, m = tid >> 6;
    int lsel = (m == 0) ? 0 : 1;

    // direct-from-global W_p B-fragments (L2-resident image)
    s16x8 pf[4][2];
    #pragma unroll
    for (int nt = 0; nt < 4; ++nt)
        #pragma unroll
        for (int ks = 0; ks < 2; ++ks)
            pf[nt][ks] = *(const s16x8*)(wimg + 29696 +
                (lsel * 64 + nt * 16 + (lane & 15)) * 72 + ks * 32 + (lane >> 4) * 8);

    for (int i = tid; i < 1152; i += 256)
        ((s16x8*)sWl)[i] = ((const s16x8*)(wimg + 20480))[i];
    for (int i = tid; i < 1280; i += 256)
        sWc[i >= 640][i % 640] = (i >= 640 ? W_c1 : W_c0)[i % 640];
    if (tid < 32) {
        int nn = n0 + tid, e = 0;
        for (int a = 0; a < 10; ++a)
            if (one_hot[(size_t)nn * 10 + a] > 0.5f) { e = a; break; }
        sElem[tid] = e;
    }
    __syncthreads();

    // sc0 skip connection: 8 threads per node, 8 k's per thread, bf16 W_skip
    {
        int nl = tid >> 3, k0 = (tid & 7) * 8;
        int nn = n0 + nl, elem = sElem[nl];
        float acc[8] = {0, 0, 0, 0, 0, 0, 0, 0};
        const ushort* wskb = wimg + 38912;
        for (int c = 0; c < 64; ++c) {
            float v = nf[(size_t)nn * 64 + c];
            s16x8 w = *(const s16x8*)(wskb + ((size_t)c * 10 + elem) * 64 + k0);
            #pragma unroll
            for (int j = 0; j < 8; ++j) acc[j] += v * bf2f((ushort)w[j]);
        }
        #pragma unroll
        for (int j = 0; j < 8; ++j) sSc[nl][k0 + j] = acc[j];
    }

    // GEMM1: feats[m] = agg[:,m,:] @ W_lin[lsel]   (M=32, K=64, N=64)
    f32x4 acc[2][4] = {};
    s16x8 afr[2][2];
    #pragma unroll
    for (int mt = 0; mt < 2; ++mt)
        #pragma unroll
        for (int ks = 0; ks < 2; ++ks)
            afr[mt][ks] = *(const s16x8*)(agg +
                (((size_t)(n0 + mt * 16 + (lane & 15))) * 4 + m) * 64 +
                ks * 32 + (lane >> 4) * 8);
    #pragma unroll
    for (int nt = 0; nt < 4; ++nt)
        #pragma unroll
        for (int ks = 0; ks < 2; ++ks) {
            s16x8 b = *(const s16x8*)(sWl + (lsel * 64 + nt * 16 + (lane & 15)) * 72 +
                                      ks * 32 + (lane >> 4) * 8);
            #pragma unroll
            for (int mt = 0; mt < 2; ++mt)
                acc[mt][nt] = __builtin_amdgcn_mfma_f32_16x16x32_bf16(afr[mt][ks], b,
                                                                      acc[mt][nt], 0, 0, 0);
        }

    // scale by wn and write bf16 to sF
    #pragma unroll
    for (int mt = 0; mt < 2; ++mt)
        #pragma unroll
        for (int nt = 0; nt < 4; ++nt)
            #pragma unroll
            for (int r = 0; r < 4; ++r) {
                int nl = mt * 16 + (lane >> 4) * 4 + r;
                int k = nt * 16 + (lane & 15);
                float scale = sWc[lsel][sElem[nl] * 64 + k];
                sF[m][nl * 72 + k] = f2bf(acc[mt][nt][r] * scale);
            }
    __syncthreads();

    // GEMM2: out_m = f[m] @ W_p{0|1}
    f32x4 acc2[2][4] = {};
    s16x8 af2[2][2];
    #pragma unroll
    for (int mt = 0; mt < 2; ++mt)
        #pragma unroll
        for (int ks = 0; ks < 2; ++ks)
            af2[mt][ks] = *(const s16x8*)(&sF[m][(mt * 16 + (lane & 15)) * 72 +
                                                 ks * 32 + (lane >> 4) * 8]);
    #pragma unroll
    for (int nt = 0; nt < 4; ++nt)
        #pragma unroll
        for (int ks = 0; ks < 2; ++ks) {
            #pragma unroll
            for (int mt = 0; mt < 2; ++mt)
                acc2[mt][nt] = __builtin_amdgcn_mfma_f32_16x16x32_bf16(af2[mt][ks],
                                                                       pf[nt][ks],
                                                                       acc2[mt][nt], 0, 0, 0);
        }

    // epilogue
    #pragma unroll
    for (int mt = 0; mt < 2; ++mt)
        #pragma unroll
        for (int nt = 0; nt < 4; ++nt)
            #pragma unroll
            for (int r = 0; r < 4; ++r) {
                int nl = mt * 16 + (lane >> 4) * 4 + r;
                int k = nt * 16 + (lane & 15);
                size_t nn = (size_t)n0 + nl;
                if (m == 0)
                    out[nn * 256 + k] = acc2[mt][nt][r] + sSc[nl][k];
                else
                    out[nn * 256 + 64 + k * 3 + (m - 1)] = acc2[mt][nt][r];
            }
}

extern "C" void kernel_launch(void* const* d_in, const int* in_sizes, int n_in,
                              void* d_out, int out_size, void* d_ws, size_t ws_size,
                              hipStream_t stream) {
    const float* node_features = (const float*)d_in[0];
    const float* one_hot = (const float*)d_in[1];
    const float* angular = (const float*)d_in[2];
    const float* radial = (const float*)d_in[3];
    const float* W_up = (const float*)d_in[4];
    const float* W_mlp1 = (const float*)d_in[5];
    const float* W_mlp2 = (const float*)d_in[6];
    const float* W_mlp3 = (const float*)d_in[7];
    const float* W_mlp4 = (const float*)d_in[8];
    const float* W_lin = (const float*)d_in[9];
    const float* W_skip = (const float*)d_in[10];
    const float* W_c0 = (const float*)d_in[11];
    const float* W_c1 = (const float*)d_in[12];
    const float* W_p0 = (const float*)d_in[13];
    const float* W_p1 = (const float*)d_in[14];
    const int* edge_index = (const int*)d_in[15];
    float* out = (float*)d_out;

    int N = in_sizes[0] / 64;
    int E = in_sizes[2] / 16;
    const int* sender = edge_index;
    const int* receiver = edge_index + E;

    char* p = (char*)d_ws;
    ushort* x_ws = (ushort*)p;      p += (size_t)N * 64 * 2;
    unsigned* tpw32 = (unsigned*)p; p += (size_t)E * 64 * 4;
    ushort* agg = (ushort*)p;       p += (size_t)N * 256 * 2;
    ushort* wimg = (ushort*)p;      p += 79872 * 2;
    int* counts = (int*)p;          p += (size_t)N * 4;
    int* offsets = (int*)p;         p += (size_t)(N + 1) * 4;
    int* cursor = (int*)p;          p += (size_t)N * 4;
    int* csr_eid = (int*)p;         p += (size_t)E * 4;

    prep_up_kernel<<<N / 32 + 312, 256, 0, stream>>>(node_features, W_up, x_ws,
                                                     W_mlp1, W_mlp2, W_mlp3, W_mlp4,
                                                     W_lin, W_p0, W_p1, W_skip, wimg,
                                                     counts, N);
    hist_kernel<<<(E + 255) / 256, 256, 0, stream>>>(receiver, counts, E);
    scan_kernel<<<1, 1024, 0, stream>>>(counts, offsets, cursor, N);
    edge_mlp_kernel<<<(E + 127) / 128, 256, 0, stream>>>(receiver, radial, cursor,
                                                         csr_eid, wimg, tpw32, E);
    agg_kernel<<<(N + 3) / 4, 256, 0, stream>>>(angular, sender, csr_eid, tpw32,
                                                offsets, x_ws, agg, N);
    node_out2_kernel<<<N / 32, 256, 0, stream>>>(node_features, one_hot, wimg,
                                                 W_c0, W_c1, agg, out);
}

// Round 12
// 107.940 us; speedup vs baseline: 1.1115x; 1.1115x over previous
//
#include <hip/hip_runtime.h>

typedef __attribute__((ext_vector_type(8))) short s16x8;
typedef __attribute__((ext_vector_type(4))) float f32x4;

__device__ inline float bf2f(ushort u) {
    union { unsigned int i; float f; } v; v.i = ((unsigned)u) << 16; return v.f;
}
__device__ inline float u2f(unsigned u) {
    union { unsigned int i; float f; } v; v.i = u; return v.f;
}
__device__ inline ushort f2bf(float f) {
    union { float f; unsigned int i; } v; v.f = f;
    unsigned r = v.i + 0x7FFFu + ((v.i >> 16) & 1u);
    return (ushort)(r >> 16);
}
__device__ inline unsigned cvt_pk(float lo, float hi) {
    unsigned d;
    asm("v_cvt_pk_bf16_f32 %0, %1, %2" : "=v"(d) : "v"(lo), "v"(hi));
    return d;
}
// fast silu: x * rcp(1 + 2^(-x*log2e)) — 5 VALU ops, correct at +-inf
__device__ inline float silu_f(float x) {
    float e;
    asm("v_exp_f32 %0, %1" : "=v"(e) : "v"(x * -1.44269504f));
    float d = 1.f + e, r;
    asm("v_rcp_f32 %0, %1" : "=v"(r) : "v"(d));
    return x * r;
}

// K1 merged: blocks [0, N/32) do node_up (32 nodes/block); rest do prep+counts.
// wimg ushort layout:
//   [0,4096)       W1t  (64m x 64k, k<8 real else 0), A-side swizzle
//   [4096,8192)    W2t  (64 x 64)
//   [8192,12288)   W3t  (64 x 64)
//   [12288,20480)  W4t  (128m x 64k)
//   [20480,29696)  wl_img: (l*64+col)*72 + c  = W_lin[l][c][col]
//   [29696,38912)  wp_img: (l*64+col)*72 + c  = W_p{l}[c][col]
//   [38912,79872)  wskb: W_skip bf16 linear (c*10+a)*64+k
__global__ __launch_bounds__(256) void prep_up_kernel(
    const float* __restrict__ nf, const float* __restrict__ W_up,
    ushort* __restrict__ x_ws,
    const float* __restrict__ W1, const float* __restrict__ W2,
    const float* __restrict__ W3, const float* __restrict__ W4,
    const float* __restrict__ W_lin, const float* __restrict__ Wp0,
    const float* __restrict__ Wp1, const float* __restrict__ W_skip,
    ushort* __restrict__ wimg, int* __restrict__ counts, int N) {
    __shared__ float sW[64 * 64];
    __shared__ float sNf[32][64];
    int tid = threadIdx.x;
    int nub = N / 32;
    if ((int)blockIdx.x < nub) {
        size_t n0 = (size_t)blockIdx.x * 32;
        for (int i = tid; i < 4096; i += 256) sW[i] = W_up[i];
        for (int i = tid; i < 2048; i += 256) {
            int r = i >> 6, c = i & 63;
            sNf[r][c] = nf[(n0 + r) * 64 + c];
        }
        __syncthreads();
        int r = tid >> 3, k0 = (tid & 7) * 8;
        float acc[8] = {0, 0, 0, 0, 0, 0, 0, 0};
        #pragma unroll 4
        for (int c = 0; c < 64; ++c) {
            float v = sNf[r][c];
            const float* wr = &sW[c * 64 + k0];
            #pragma unroll
            for (int j = 0; j < 8; ++j) acc[j] += v * wr[j];
        }
        uint4 val;
        val.x = cvt_pk(acc[0], acc[1]);
        val.y = cvt_pk(acc[2], acc[3]);
        val.z = cvt_pk(acc[4], acc[5]);
        val.w = cvt_pk(acc[6], acc[7]);
        *(uint4*)(x_ws + (n0 + r) * 64 + k0) = val;
        return;
    }
    int idx = ((int)blockIdx.x - nub) * 256 + tid;
    if (idx < N) counts[idx] = 0;
    if (idx < 4096) {
        int m = idx >> 6, k = idx & 63;
        int dst = m * 64 + ((((k >> 3) ^ (m & 7))) << 3) + (k & 7);
        wimg[dst] = (k < 8) ? f2bf(W1[k * 64 + m]) : (ushort)0;
    } else if (idx < 8192) {
        int i = idx - 4096;
        int m = i >> 6, k = i & 63;
        int dst = 4096 + m * 64 + ((((k >> 3) ^ (m & 7))) << 3) + (k & 7);
        wimg[dst] = f2bf(W2[k * 64 + m]);
    } else if (idx < 12288) {
        int i = idx - 8192;
        int m = i >> 6, k = i & 63;
        int dst = 8192 + m * 64 + ((((k >> 3) ^ (m & 7))) << 3) + (k & 7);
        wimg[dst] = f2bf(W3[k * 64 + m]);
    } else if (idx < 20480) {
        int i = idx - 12288;
        int m = i >> 6, k = i & 63;  // m in 0..127
        int dst = 12288 + m * 64 + ((((k >> 3) ^ (m & 7))) << 3) + (k & 7);
        wimg[dst] = f2bf(W4[k * 256 + m]);
    } else if (idx < 29696) {
        int i = idx - 20480;
        int row = i / 72, k = i % 72;
        int l = row >> 6, col = row & 63;
        wimg[idx] = (k < 64) ? f2bf(W_lin[l * 4096 + k * 64 + col]) : (ushort)0;
    } else if (idx < 38912) {
        int i = idx - 29696;
        int row = i / 72, k = i % 72;
        int l = row >> 6, col = row & 63;
        const float* Wp = l ? Wp1 : Wp0;
        wimg[idx] = (k < 64) ? f2bf(Wp[k * 64 + col]) : (ushort)0;
    } else if (idx < 79872) {
        int i = idx - 38912;
        wimg[idx] = f2bf(W_skip[i]);
    }
}

// K2: histogram of receivers + per-edge local rank (old count value)
__global__ __launch_bounds__(256) void hist_kernel(const int* __restrict__ recv,
                                                   int* __restrict__ counts,
                                                   int* __restrict__ rank, int E) {
    int e = blockIdx.x * 256 + threadIdx.x;
    if (e < E) rank[e] = atomicAdd(&counts[recv[e]], 1);
}

// K3: single-pass chunked exclusive scan counts -> offsets
__global__ __launch_bounds__(1024) void scan_kernel(const int* __restrict__ counts,
                                                    int* __restrict__ offsets, int n) {
    __shared__ int wsums[16];
    int tid = threadIdx.x, lane = tid & 63, wid = tid >> 6;
    int CH = (n + 1023) >> 10;
    int base = tid * CH;
    int cnt[20];
    int tot = 0;
    if (CH <= 20) {
        #pragma unroll
        for (int j = 0; j < 20; ++j) {
            int i = base + j;
            cnt[j] = (j < CH && i < n) ? counts[i] : 0;
            tot += cnt[j];
        }
    } else {
        for (int j = 0; j < CH; ++j) {
            int i = base + j;
            if (i < n) tot += counts[i];
        }
    }
    int v = tot;
    for (int off = 1; off < 64; off <<= 1) {
        int t = __shfl_up(v, off, 64);
        if (lane >= off) v += t;
    }
    if (lane == 63) wsums[wid] = v;
    __syncthreads();
    if (tid == 0) {
        int acc = 0;
        for (int w = 0; w < 16; ++w) { int t = wsums[w]; wsums[w] = acc; acc += t; }
    }
    __syncthreads();
    int excl = wsums[wid] + v - tot;
    if (CH <= 20) {
        #pragma unroll
        for (int j = 0; j < 20; ++j) {
            int i = base + j;
            if (j < CH && i < n) { offsets[i] = excl; excl += cnt[j]; }
        }
    } else {
        for (int j = 0; j < CH; ++j) {
            int i = base + j;
            if (i < n) { offsets[i] = excl; excl += counts[i]; }
        }
    }
    if (tid == 1023) offsets[n] = excl;
}

// K5: edge MLP, dual-group interleaved (wave owns 32 edges = groups A,B of 16,
// processed in ONE pass with interleaved independent chains). Weights streamed
// directly from L2-resident wimg (single-use). No barriers, no atomics:
// CSR position = offsets[recv[e]] + rank[e] (4B scatter, hi==0 lanes).
__global__ __launch_bounds__(256) void edge_mlp_kernel(
    const int* __restrict__ recv, const int* __restrict__ rank,
    const int* __restrict__ offsets, const float* __restrict__ radial,
    int* __restrict__ csr_eid, const ushort* __restrict__ wimg,
    unsigned* __restrict__ tpw32, int E) {
    __shared__ __align__(16) ushort sB[4][2048];  // per-wave 4KB: A | B bounce
    int tid = threadIdx.x, lane = tid & 63, wave = tid >> 6;
    int n = lane & 15, hi = lane >> 4;
    int base = blockIdx.x * 128 + wave * 32;
    if (base >= E) return;
    int eA = base + n, eB = base + 16 + n;
    bool okA = eA < E, okB = eB < E;
    int eAc = min(eA, E - 1), eBc = min(eB, E - 1);

    char* bAq = (char*)sB[wave];
    char* bBq = (char*)sB[wave] + 2048;
    int n7 = n & 7;

    // radial fragments + CSR position scatter (hi==0 lanes)
    s16x8 bRA, bRB;
    #pragma unroll
    for (int j = 0; j < 8; ++j) { bRA[j] = 0; bRB[j] = 0; }
    if (hi == 0) {
        float4 a0 = *(const float4*)(radial + (size_t)eAc * 8);
        float4 a1 = *(const float4*)(radial + (size_t)eAc * 8 + 4);
        float4 c0 = *(const float4*)(radial + (size_t)eBc * 8);
        float4 c1 = *(const float4*)(radial + (size_t)eBc * 8 + 4);
        union { s16x8 v; uint4 u; } pa, pb;
        pa.u.x = cvt_pk(a0.x, a0.y); pa.u.y = cvt_pk(a0.z, a0.w);
        pa.u.z = cvt_pk(a1.x, a1.y); pa.u.w = cvt_pk(a1.z, a1.w);
        pb.u.x = cvt_pk(c0.x, c0.y); pb.u.y = cvt_pk(c0.z, c0.w);
        pb.u.z = cvt_pk(c1.x, c1.y); pb.u.w = cvt_pk(c1.z, c1.w);
        bRA = pa.v; bRB = pb.v;
        if (okA) csr_eid[offsets[recv[eA]] + rank[eA]] = eA;
        if (okB) csr_eid[offsets[recv[eB]] + rank[eB]] = eB;
    }

    f32x4 zero = {0.f, 0.f, 0.f, 0.f};
    f32x4 dA[4], dB[4];

    // L1 (K=32, zero-padded radial), weights streamed from wimg[0..4096)
    #pragma unroll
    for (int mt = 0; mt < 4; ++mt) {
        int row = mt * 16 + n, r7 = row & 7;
        s16x8 w = *(const s16x8*)(wimg + row * 64 + ((hi ^ r7) << 3));
        dA[mt] = __builtin_amdgcn_mfma_f32_16x16x32_bf16(w, bRA, zero, 0, 0, 0);
        dB[mt] = __builtin_amdgcn_mfma_f32_16x16x32_bf16(w, bRB, zero, 0, 0, 0);
    }
    #pragma unroll
    for (int mt = 0; mt < 4; ++mt) {
        int slot = mt * 2 + (hi >> 1);
        int off = ((slot ^ n7) << 4) + (hi & 1) * 8;
        uint2 vA = {cvt_pk(silu_f(dA[mt][0]), silu_f(dA[mt][1])),
                    cvt_pk(silu_f(dA[mt][2]), silu_f(dA[mt][3]))};
        *(uint2*)(bAq + n * 128 + off) = vA;
        uint2 vB = {cvt_pk(silu_f(dB[mt][0]), silu_f(dB[mt][1])),
                    cvt_pk(silu_f(dB[mt][2]), silu_f(dB[mt][3]))};
        *(uint2*)(bBq + n * 128 + off) = vB;
    }
    s16x8 b0A = *(const s16x8*)(bAq + n * 128 + ((hi ^ n7) << 4));
    s16x8 b1A = *(const s16x8*)(bAq + n * 128 + (((4 + hi) ^ n7) << 4));
    s16x8 b0B = *(const s16x8*)(bBq + n * 128 + ((hi ^ n7) << 4));
    s16x8 b1B = *(const s16x8*)(bBq + n * 128 + (((4 + hi) ^ n7) << 4));

    // L2, weights wimg[4096..8192)
    #pragma unroll
    for (int mt = 0; mt < 4; ++mt) {
        int row = mt * 16 + n, r7 = row & 7;
        s16x8 w0 = *(const s16x8*)(wimg + 4096 + row * 64 + ((hi ^ r7) << 3));
        s16x8 w1 = *(const s16x8*)(wimg + 4096 + row * 64 + (((4 + hi) ^ r7) << 3));
        dA[mt] = __builtin_amdgcn_mfma_f32_16x16x32_bf16(w0, b0A, zero, 0, 0, 0);
        dA[mt] = __builtin_amdgcn_mfma_f32_16x16x32_bf16(w1, b1A, dA[mt], 0, 0, 0);
        dB[mt] = __builtin_amdgcn_mfma_f32_16x16x32_bf16(w0, b0B, zero, 0, 0, 0);
        dB[mt] = __builtin_amdgcn_mfma_f32_16x16x32_bf16(w1, b1B, dB[mt], 0, 0, 0);
    }
    #pragma unroll
    for (int mt = 0; mt < 4; ++mt) {
        int slot = mt * 2 + (hi >> 1);
        int off = ((slot ^ n7) << 4) + (hi & 1) * 8;
        uint2 vA = {cvt_pk(silu_f(dA[mt][0]), silu_f(dA[mt][1])),
                    cvt_pk(silu_f(dA[mt][2]), silu_f(dA[mt][3]))};
        *(uint2*)(bAq + n * 128 + off) = vA;
        uint2 vB = {cvt_pk(silu_f(dB[mt][0]), silu_f(dB[mt][1])),
                    cvt_pk(silu_f(dB[mt][2]), silu_f(dB[mt][3]))};
        *(uint2*)(bBq + n * 128 + off) = vB;
    }
    b0A = *(const s16x8*)(bAq + n * 128 + ((hi ^ n7) << 4));
    b1A = *(const s16x8*)(bAq + n * 128 + (((4 + hi) ^ n7) << 4));
    b0B = *(const s16x8*)(bBq + n * 128 + ((hi ^ n7) << 4));
    b1B = *(const s16x8*)(bBq + n * 128 + (((4 + hi) ^ n7) << 4));

    // L3, weights wimg[8192..12288)
    #pragma unroll
    for (int mt = 0; mt < 4; ++mt) {
        int row = mt * 16 + n, r7 = row & 7;
        s16x8 w0 = *(const s16x8*)(wimg + 8192 + row * 64 + ((hi ^ r7) << 3));
        s16x8 w1 = *(const s16x8*)(wimg + 8192 + row * 64 + (((4 + hi) ^ r7) << 3));
        dA[mt] = __builtin_amdgcn_mfma_f32_16x16x32_bf16(w0, b0A, zero, 0, 0, 0);
        dA[mt] = __builtin_amdgcn_mfma_f32_16x16x32_bf16(w1, b1A, dA[mt], 0, 0, 0);
        dB[mt] = __builtin_amdgcn_mfma_f32_16x16x32_bf16(w0, b0B, zero, 0, 0, 0);
        dB[mt] = __builtin_amdgcn_mfma_f32_16x16x32_bf16(w1, b1B, dB[mt], 0, 0, 0);
    }
    #pragma unroll
    for (int mt = 0; mt < 4; ++mt) {
        int slot = mt * 2 + (hi >> 1);
        int off = ((slot ^ n7) << 4) + (hi & 1) * 8;
        uint2 vA = {cvt_pk(silu_f(dA[mt][0]), silu_f(dA[mt][1])),
                    cvt_pk(silu_f(dA[mt][2]), silu_f(dA[mt][3]))};
        *(uint2*)(bAq + n * 128 + off) = vA;
        uint2 vB = {cvt_pk(silu_f(dB[mt][0]), silu_f(dB[mt][1])),
                    cvt_pk(silu_f(dB[mt][2]), silu_f(dB[mt][3]))};
        *(uint2*)(bBq + n * 128 + off) = vB;
    }
    b0A = *(const s16x8*)(bAq + n * 128 + ((hi ^ n7) << 4));
    b1A = *(const s16x8*)(bAq + n * 128 + (((4 + hi) ^ n7) << 4));
    b0B = *(const s16x8*)(bBq + n * 128 + ((hi ^ n7) << 4));
    b1B = *(const s16x8*)(bBq + n * 128 + (((4 + hi) ^ n7) << 4));

    // L4: 128 outputs (l=0,1), weights wimg[12288..20480); contiguous stores.
    size_t rbA = (size_t)eA * 64, rbB = (size_t)eB * 64;
    const ushort* w4 = wimg + 12288;
    #pragma unroll
    for (int mt = 0; mt < 4; ++mt) {
        int row0 = mt * 16 + n, r70 = row0 & 7;
        int row1 = (mt + 4) * 16 + n, r71 = row1 & 7;
        s16x8 a0lo = *(const s16x8*)(w4 + row0 * 64 + ((hi ^ r70) << 3));
        s16x8 a1lo = *(const s16x8*)(w4 + row0 * 64 + (((4 + hi) ^ r70) << 3));
        s16x8 a0hi = *(const s16x8*)(w4 + row1 * 64 + ((hi ^ r71) << 3));
        s16x8 a1hi = *(const s16x8*)(w4 + row1 * 64 + (((4 + hi) ^ r71) << 3));
        f32x4 oloA = __builtin_amdgcn_mfma_f32_16x16x32_bf16(a0lo, b0A, zero, 0, 0, 0);
        oloA = __builtin_amdgcn_mfma_f32_16x16x32_bf16(a1lo, b1A, oloA, 0, 0, 0);
        f32x4 ohiA = __builtin_amdgcn_mfma_f32_16x16x32_bf16(a0hi, b0A, zero, 0, 0, 0);
        ohiA = __builtin_amdgcn_mfma_f32_16x16x32_bf16(a1hi, b1A, ohiA, 0, 0, 0);
        f32x4 oloB = __builtin_amdgcn_mfma_f32_16x16x32_bf16(a0lo, b0B, zero, 0, 0, 0);
        oloB = __builtin_amdgcn_mfma_f32_16x16x32_bf16(a1lo, b1B, oloB, 0, 0, 0);
        f32x4 ohiB = __builtin_amdgcn_mfma_f32_16x16x32_bf16(a0hi, b0B, zero, 0, 0, 0);
        ohiB = __builtin_amdgcn_mfma_f32_16x16x32_bf16(a1hi, b1B, ohiB, 0, 0, 0);
        if (okA) {
            uint4 val;
            val.x = cvt_pk(oloA[0], ohiA[0]);
            val.y = cvt_pk(oloA[1], ohiA[1]);
            val.z = cvt_pk(oloA[2], ohiA[2]);
            val.w = cvt_pk(oloA[3], ohiA[3]);
            *(uint4*)(tpw32 + rbA + mt * 16 + hi * 4) = val;
        }
        if (okB) {
            uint4 val;
            val.x = cvt_pk(oloB[0], ohiB[0]);
            val.y = cvt_pk(oloB[1], ohiB[1]);
            val.z = cvt_pk(oloB[2], ohiB[2]);
            val.w = cvt_pk(oloB[3], ohiB[3]);
            *(uint4*)(tpw32 + rbB + mt * 16 + hi * 4) = val;
        }
    }
}

// K6a: CSR aggregation with eid indirection. Wave per node, lane = channel.
// 4-edge batched loads hide L2/L3 gather latency.
__global__ __launch_bounds__(256) void agg_kernel(const float* __restrict__ angular,
                                                  const int* __restrict__ sender,
                                                  const int* __restrict__ csr_eid,
                                                  const unsigned* __restrict__ tpw32,
                                                  const int* __restrict__ offsets,
                                                  const ushort* __restrict__ x_ws,
                                                  ushort* __restrict__ agg, int N) {
    int wave = threadIdx.x >> 6, lane = threadIdx.x & 63;
    int node = blockIdx.x * 4 + wave;
    if (node >= N) return;
    int beg = offsets[node], end = offsets[node + 1];
    float a0 = 0, a1 = 0, a2 = 0, a3 = 0;
    for (int cb = beg; cb < end; cb += 64) {
        int m = min(64, end - cb);
        int ev = csr_eid[cb + min(lane, m - 1)];
        int sv = sender[ev];
        for (int e0 = 0; e0 < m; e0 += 4) {
            unsigned t[4];
            ushort x[4];
            float4 g[4];
            #pragma unroll
            for (int j = 0; j < 4; ++j) {
                int e = e0 + j;
                int ec = min(e, m - 1);
                int eidj = __shfl(ev, ec);
                t[j] = tpw32[(size_t)eidj * 64 + lane];
                x[j] = x_ws[(size_t)__shfl(sv, ec) * 64 + lane];
                if (e < m) g[j] = *(const float4*)(angular + (size_t)eidj * 16);
                else g[j] = make_float4(0.f, 0.f, 0.f, 0.f);
            }
            #pragma unroll
            for (int j = 0; j < 4; ++j) {
                float xv = bf2f(x[j]);
                float tp0 = u2f(t[j] << 16);
                float tp1 = u2f(t[j] & 0xffff0000u);
                float y0 = xv * tp0, y1 = xv * tp1;
                a0 += g[j].x * y0;
                a1 += g[j].y * y1;
                a2 += g[j].z * y1;
                a3 += g[j].w * y1;
            }
        }
    }
    size_t b = (size_t)node * 256 + lane;
    agg[b] = f2bf(a0 * 0.1f);
    agg[b + 64] = f2bf(a1 * 0.1f);
    agg[b + 128] = f2bf(a2 * 0.1f);
    agg[b + 192] = f2bf(a3 * 0.1f);
}

// K6b: per-32-node tile: feats = agg@W_lin (MFMA), scale by wn, out = f@W_p (+sc0).
__global__ __launch_bounds__(256) void node_out2_kernel(
    const float* __restrict__ nf, const float* __restrict__ one_hot,
    const ushort* __restrict__ wimg, const float* __restrict__ W_c0,
    const float* __restrict__ W_c1, const ushort* __restrict__ agg,
    float* __restrict__ out) {
    __shared__ __align__(16) ushort sWl[2 * 64 * 72];
    __shared__ __align__(16) ushort sF[4][32 * 72];
    __shared__ float sSc[32][64];
    __shared__ float sWc[2][640];
    __shared__ int sElem[32];
    int tid = threadIdx.x;
    int n0 = blockIdx.x * 32;
    int lane = tid & 63, m = tid >> 6;
    int lsel = (m == 0) ? 0 : 1;

    // direct-from-global W_p B-fragments (L2-resident image)
    s16x8 pf[4][2];
    #pragma unroll
    for (int nt = 0; nt < 4; ++nt)
        #pragma unroll
        for (int ks = 0; ks < 2; ++ks)
            pf[nt][ks] = *(const s16x8*)(wimg + 29696 +
                (lsel * 64 + nt * 16 + (lane & 15)) * 72 + ks * 32 + (lane >> 4) * 8);

    for (int i = tid; i < 1152; i += 256)
        ((s16x8*)sWl)[i] = ((const s16x8*)(wimg + 20480))[i];
    for (int i = tid; i < 1280; i += 256)
        sWc[i >= 640][i % 640] = (i >= 640 ? W_c1 : W_c0)[i % 640];
    if (tid < 32) {
        int nn = n0 + tid, e = 0;
        for (int a = 0; a < 10; ++a)
            if (one_hot[(size_t)nn * 10 + a] > 0.5f) { e = a; break; }
        sElem[tid] = e;
    }
    __syncthreads();

    // sc0 skip connection: 8 threads per node, 8 k's per thread, bf16 W_skip
    {
        int nl = tid >> 3, k0 = (tid & 7) * 8;
        int nn = n0 + nl, elem = sElem[nl];
        float acc[8] = {0, 0, 0, 0, 0, 0, 0, 0};
        const ushort* wskb = wimg + 38912;
        for (int c = 0; c < 64; ++c) {
            float v = nf[(size_t)nn * 64 + c];
            s16x8 w = *(const s16x8*)(wskb + ((size_t)c * 10 + elem) * 64 + k0);
            #pragma unroll
            for (int j = 0; j < 8; ++j) acc[j] += v * bf2f((ushort)w[j]);
        }
        #pragma unroll
        for (int j = 0; j < 8; ++j) sSc[nl][k0 + j] = acc[j];
    }

    // GEMM1: feats[m] = agg[:,m,:] @ W_lin[lsel]   (M=32, K=64, N=64)
    f32x4 acc[2][4] = {};
    s16x8 afr[2][2];
    #pragma unroll
    for (int mt = 0; mt < 2; ++mt)
        #pragma unroll
        for (int ks = 0; ks < 2; ++ks)
            afr[mt][ks] = *(const s16x8*)(agg +
                (((size_t)(n0 + mt * 16 + (lane & 15))) * 4 + m) * 64 +
                ks * 32 + (lane >> 4) * 8);
    #pragma unroll
    for (int nt = 0; nt < 4; ++nt)
        #pragma unroll
        for (int ks = 0; ks < 2; ++ks) {
            s16x8 b = *(const s16x8*)(sWl + (lsel * 64 + nt * 16 + (lane & 15)) * 72 +
                                      ks * 32 + (lane >> 4) * 8);
            #pragma unroll
            for (int mt = 0; mt < 2; ++mt)
                acc[mt][nt] = __builtin_amdgcn_mfma_f32_16x16x32_bf16(afr[mt][ks], b,
                                                                      acc[mt][nt], 0, 0, 0);
        }

    // scale by wn and write bf16 to sF
    #pragma unroll
    for (int mt = 0; mt < 2; ++mt)
        #pragma unroll
        for (int nt = 0; nt < 4; ++nt)
            #pragma unroll
            for (int r = 0; r < 4; ++r) {
                int nl = mt * 16 + (lane >> 4) * 4 + r;
                int k = nt * 16 + (lane & 15);
                float scale = sWc[lsel][sElem[nl] * 64 + k];
                sF[m][nl * 72 + k] = f2bf(acc[mt][nt][r] * scale);
            }
    __syncthreads();

    // GEMM2: out_m = f[m] @ W_p{0|1}
    f32x4 acc2[2][4] = {};
    s16x8 af2[2][2];
    #pragma unroll
    for (int mt = 0; mt < 2; ++mt)
        #pragma unroll
        for (int ks = 0; ks < 2; ++ks)
            af2[mt][ks] = *(const s16x8*)(&sF[m][(mt * 16 + (lane & 15)) * 72 +
                                                 ks * 32 + (lane >> 4) * 8]);
    #pragma unroll
    for (int nt = 0; nt < 4; ++nt)
        #pragma unroll
        for (int ks = 0; ks < 2; ++ks) {
            #pragma unroll
            for (int mt = 0; mt < 2; ++mt)
                acc2[mt][nt] = __builtin_amdgcn_mfma_f32_16x16x32_bf16(af2[mt][ks],
                                                                       pf[nt][ks],
                                                                       acc2[mt][nt], 0, 0, 0);
        }

    // epilogue
    #pragma unroll
    for (int mt = 0; mt < 2; ++mt)
        #pragma unroll
        for (int nt = 0; nt < 4; ++nt)
            #pragma unroll
            for (int r = 0; r < 4; ++r) {
                int nl = mt * 16 + (lane >> 4) * 4 + r;
                int k = nt * 16 + (lane & 15);
                size_t nn = (size_t)n0 + nl;
                if (m == 0)
                    out[nn * 256 + k] = acc2[mt][nt][r] + sSc[nl][k];
                else
                    out[nn * 256 + 64 + k * 3 + (m - 1)] = acc2[mt][nt][r];
            }
}

extern "C" void kernel_launch(void* const* d_in, const int* in_sizes, int n_in,
                              void* d_out, int out_size, void* d_ws, size_t ws_size,
                              hipStream_t stream) {
    const float* node_features = (const float*)d_in[0];
    const float* one_hot = (const float*)d_in[1];
    const float* angular = (const float*)d_in[2];
    const float* radial = (const float*)d_in[3];
    const float* W_up = (const float*)d_in[4];
    const float* W_mlp1 = (const float*)d_in[5];
    const float* W_mlp2 = (const float*)d_in[6];
    const float* W_mlp3 = (const float*)d_in[7];
    const float* W_mlp4 = (const float*)d_in[8];
    const float* W_lin = (const float*)d_in[9];
    const float* W_skip = (const float*)d_in[10];
    const float* W_c0 = (const float*)d_in[11];
    const float* W_c1 = (const float*)d_in[12];
    const float* W_p0 = (const float*)d_in[13];
    const float* W_p1 = (const float*)d_in[14];
    const int* edge_index = (const int*)d_in[15];
    float* out = (float*)d_out;

    int N = in_sizes[0] / 64;
    int E = in_sizes[2] / 16;
    const int* sender = edge_index;
    const int* receiver = edge_index + E;

    char* p = (char*)d_ws;
    ushort* x_ws = (ushort*)p;      p += (size_t)N * 64 * 2;
    unsigned* tpw32 = (unsigned*)p; p += (size_t)E * 64 * 4;
    ushort* agg = (ushort*)p;       p += (size_t)N * 256 * 2;
    ushort* wimg = (ushort*)p;      p += 79872 * 2;
    int* counts = (int*)p;          p += (size_t)N * 4;
    int* offsets = (int*)p;         p += (size_t)(N + 1) * 4;
    int* rank = (int*)p;            p += (size_t)E * 4;
    int* csr_eid = (int*)p;         p += (size_t)E * 4;

    prep_up_kernel<<<N / 32 + 312, 256, 0, stream>>>(node_features, W_up, x_ws,
                                                     W_mlp1, W_mlp2, W_mlp3, W_mlp4,
                                                     W_lin, W_p0, W_p1, W_skip, wimg,
                                                     counts, N);
    hist_kernel<<<(E + 255) / 256, 256, 0, stream>>>(receiver, counts, rank, E);
    scan_kernel<<<1, 1024, 0, stream>>>(counts, offsets, N);
    edge_mlp_kernel<<<(E + 127) / 128, 256, 0, stream>>>(receiver, rank, offsets,
                                                         radial, csr_eid, wimg,
                                                         tpw32, E);
    agg_kernel<<<(N + 3) / 4, 256, 0, stream>>>(angular, sender, csr_eid, tpw32,
                                                offsets, x_ws, agg, N);
    node_out2_kernel<<<N / 32, 256, 0, stream>>>(node_features, one_hot, wimg,
                                                 W_c0, W_c1, agg, out);
}

// Round 13
// 106.431 us; speedup vs baseline: 1.1273x; 1.0142x over previous
//
#include <hip/hip_runtime.h>

typedef __attribute__((ext_vector_type(8))) short s16x8;
typedef __attribute__((ext_vector_type(4))) float f32x4;

__device__ inline float bf2f(ushort u) {
    union { unsigned int i; float f; } v; v.i = ((unsigned)u) << 16; return v.f;
}
__device__ inline float u2f(unsigned u) {
    union { unsigned int i; float f; } v; v.i = u; return v.f;
}
__device__ inline ushort f2bf(float f) {
    union { float f; unsigned int i; } v; v.f = f;
    unsigned r = v.i + 0x7FFFu + ((v.i >> 16) & 1u);
    return (ushort)(r >> 16);
}
__device__ inline unsigned cvt_pk(float lo, float hi) {
    unsigned d;
    asm("v_cvt_pk_bf16_f32 %0, %1, %2" : "=v"(d) : "v"(lo), "v"(hi));
    return d;
}
// fast silu: x * rcp(1 + 2^(-x*log2e)) — 5 VALU ops, correct at +-inf
__device__ inline float silu_f(float x) {
    float e;
    asm("v_exp_f32 %0, %1" : "=v"(e) : "v"(x * -1.44269504f));
    float d = 1.f + e, r;
    asm("v_rcp_f32 %0, %1" : "=v"(r) : "v"(d));
    return x * r;
}

// K1 merged: blocks [0, N/32) do node_up (32 nodes/block); rest do prep+counts.
// wimg ushort layout:
//   [0,4096)       W1t  (64m x 64k, k<8 real else 0), A-side swizzle
//   [4096,8192)    W2t  (64 x 64)
//   [8192,12288)   W3t  (64 x 64)
//   [12288,20480)  W4t  (128m x 64k)
//   [20480,29696)  wl_img: (l*64+col)*72 + c  = W_lin[l][c][col]
//   [29696,38912)  wp_img: (l*64+col)*72 + c  = W_p{l}[c][col]
//   [38912,79872)  wskb: W_skip bf16 linear (c*10+a)*64+k
__global__ __launch_bounds__(256) void prep_up_kernel(
    const float* __restrict__ nf, const float* __restrict__ W_up,
    ushort* __restrict__ x_ws,
    const float* __restrict__ W1, const float* __restrict__ W2,
    const float* __restrict__ W3, const float* __restrict__ W4,
    const float* __restrict__ W_lin, const float* __restrict__ Wp0,
    const float* __restrict__ Wp1, const float* __restrict__ W_skip,
    ushort* __restrict__ wimg, int* __restrict__ counts, int N) {
    __shared__ float sW[64 * 64];
    __shared__ float sNf[32][64];
    int tid = threadIdx.x;
    int nub = N / 32;
    if ((int)blockIdx.x < nub) {
        size_t n0 = (size_t)blockIdx.x * 32;
        for (int i = tid; i < 4096; i += 256) sW[i] = W_up[i];
        for (int i = tid; i < 2048; i += 256) {
            int r = i >> 6, c = i & 63;
            sNf[r][c] = nf[(n0 + r) * 64 + c];
        }
        __syncthreads();
        int r = tid >> 3, k0 = (tid & 7) * 8;
        float acc[8] = {0, 0, 0, 0, 0, 0, 0, 0};
        #pragma unroll 4
        for (int c = 0; c < 64; ++c) {
            float v = sNf[r][c];
            const float* wr = &sW[c * 64 + k0];
            #pragma unroll
            for (int j = 0; j < 8; ++j) acc[j] += v * wr[j];
        }
        uint4 val;
        val.x = cvt_pk(acc[0], acc[1]);
        val.y = cvt_pk(acc[2], acc[3]);
        val.z = cvt_pk(acc[4], acc[5]);
        val.w = cvt_pk(acc[6], acc[7]);
        *(uint4*)(x_ws + (n0 + r) * 64 + k0) = val;
        return;
    }
    int idx = ((int)blockIdx.x - nub) * 256 + tid;
    if (idx < N) counts[idx] = 0;
    if (idx < 4096) {
        int m = idx >> 6, k = idx & 63;
        int dst = m * 64 + ((((k >> 3) ^ (m & 7))) << 3) + (k & 7);
        wimg[dst] = (k < 8) ? f2bf(W1[k * 64 + m]) : (ushort)0;
    } else if (idx < 8192) {
        int i = idx - 4096;
        int m = i >> 6, k = i & 63;
        int dst = 4096 + m * 64 + ((((k >> 3) ^ (m & 7))) << 3) + (k & 7);
        wimg[dst] = f2bf(W2[k * 64 + m]);
    } else if (idx < 12288) {
        int i = idx - 8192;
        int m = i >> 6, k = i & 63;
        int dst = 8192 + m * 64 + ((((k >> 3) ^ (m & 7))) << 3) + (k & 7);
        wimg[dst] = f2bf(W3[k * 64 + m]);
    } else if (idx < 20480) {
        int i = idx - 12288;
        int m = i >> 6, k = i & 63;  // m in 0..127
        int dst = 12288 + m * 64 + ((((k >> 3) ^ (m & 7))) << 3) + (k & 7);
        wimg[dst] = f2bf(W4[k * 256 + m]);
    } else if (idx < 29696) {
        int i = idx - 20480;
        int row = i / 72, k = i % 72;
        int l = row >> 6, col = row & 63;
        wimg[idx] = (k < 64) ? f2bf(W_lin[l * 4096 + k * 64 + col]) : (ushort)0;
    } else if (idx < 38912) {
        int i = idx - 29696;
        int row = i / 72, k = i % 72;
        int l = row >> 6, col = row & 63;
        const float* Wp = l ? Wp1 : Wp0;
        wimg[idx] = (k < 64) ? f2bf(Wp[k * 64 + col]) : (ushort)0;
    } else if (idx < 79872) {
        int i = idx - 38912;
        wimg[idx] = f2bf(W_skip[i]);
    }
}

// K2: histogram of receivers + per-edge local rank (old count value)
__global__ __launch_bounds__(256) void hist_kernel(const int* __restrict__ recv,
                                                   int* __restrict__ counts,
                                                   int* __restrict__ rank, int E) {
    int e = blockIdx.x * 256 + threadIdx.x;
    if (e < E) rank[e] = atomicAdd(&counts[recv[e]], 1);
}

// K3: single-pass chunked exclusive scan counts -> offsets
__global__ __launch_bounds__(1024) void scan_kernel(const int* __restrict__ counts,
                                                    int* __restrict__ offsets, int n) {
    __shared__ int wsums[16];
    int tid = threadIdx.x, lane = tid & 63, wid = tid >> 6;
    int CH = (n + 1023) >> 10;
    int base = tid * CH;
    int cnt[20];
    int tot = 0;
    if (CH <= 20) {
        #pragma unroll
        for (int j = 0; j < 20; ++j) {
            int i = base + j;
            cnt[j] = (j < CH && i < n) ? counts[i] : 0;
            tot += cnt[j];
        }
    } else {
        for (int j = 0; j < CH; ++j) {
            int i = base + j;
            if (i < n) tot += counts[i];
        }
    }
    int v = tot;
    for (int off = 1; off < 64; off <<= 1) {
        int t = __shfl_up(v, off, 64);
        if (lane >= off) v += t;
    }
    if (lane == 63) wsums[wid] = v;
    __syncthreads();
    if (tid == 0) {
        int acc = 0;
        for (int w = 0; w < 16; ++w) { int t = wsums[w]; wsums[w] = acc; acc += t; }
    }
    __syncthreads();
    int excl = wsums[wid] + v - tot;
    if (CH <= 20) {
        #pragma unroll
        for (int j = 0; j < 20; ++j) {
            int i = base + j;
            if (j < CH && i < n) { offsets[i] = excl; excl += cnt[j]; }
        }
    } else {
        for (int j = 0; j < CH; ++j) {
            int i = base + j;
            if (i < n) { offsets[i] = excl; excl += counts[i]; }
        }
    }
    if (tid == 1023) offsets[n] = excl;
}

// K5: edge MLP, dual-group interleaved. Weights streamed from L2-resident wimg.
// No barriers/atomics. CSR metadata scatter: csr_es[pos] = {eid, sender} (int2).
__global__ __launch_bounds__(256) void edge_mlp_kernel(
    const int* __restrict__ recv, const int* __restrict__ sender,
    const int* __restrict__ rank, const int* __restrict__ offsets,
    const float* __restrict__ radial, int2* __restrict__ csr_es,
    const ushort* __restrict__ wimg, unsigned* __restrict__ tpw32, int E) {
    __shared__ __align__(16) ushort sB[4][2048];  // per-wave 4KB: A | B bounce
    int tid = threadIdx.x, lane = tid & 63, wave = tid >> 6;
    int n = lane & 15, hi = lane >> 4;
    int base = blockIdx.x * 128 + wave * 32;
    if (base >= E) return;
    int eA = base + n, eB = base + 16 + n;
    bool okA = eA < E, okB = eB < E;
    int eAc = min(eA, E - 1), eBc = min(eB, E - 1);

    char* bAq = (char*)sB[wave];
    char* bBq = (char*)sB[wave] + 2048;
    int n7 = n & 7;

    // radial fragments + CSR metadata scatter (hi==0 lanes)
    s16x8 bRA, bRB;
    #pragma unroll
    for (int j = 0; j < 8; ++j) { bRA[j] = 0; bRB[j] = 0; }
    if (hi == 0) {
        float4 a0 = *(const float4*)(radial + (size_t)eAc * 8);
        float4 a1 = *(const float4*)(radial + (size_t)eAc * 8 + 4);
        float4 c0 = *(const float4*)(radial + (size_t)eBc * 8);
        float4 c1 = *(const float4*)(radial + (size_t)eBc * 8 + 4);
        union { s16x8 v; uint4 u; } pa, pb;
        pa.u.x = cvt_pk(a0.x, a0.y); pa.u.y = cvt_pk(a0.z, a0.w);
        pa.u.z = cvt_pk(a1.x, a1.y); pa.u.w = cvt_pk(a1.z, a1.w);
        pb.u.x = cvt_pk(c0.x, c0.y); pb.u.y = cvt_pk(c0.z, c0.w);
        pb.u.z = cvt_pk(c1.x, c1.y); pb.u.w = cvt_pk(c1.z, c1.w);
        bRA = pa.v; bRB = pb.v;
        if (okA) {
            int2 es; es.x = eA; es.y = sender[eA];
            csr_es[offsets[recv[eA]] + rank[eA]] = es;
        }
        if (okB) {
            int2 es; es.x = eB; es.y = sender[eB];
            csr_es[offsets[recv[eB]] + rank[eB]] = es;
        }
    }

    f32x4 zero = {0.f, 0.f, 0.f, 0.f};
    f32x4 dA[4], dB[4];

    // L1 (K=32, zero-padded radial), weights streamed from wimg[0..4096)
    #pragma unroll
    for (int mt = 0; mt < 4; ++mt) {
        int row = mt * 16 + n, r7 = row & 7;
        s16x8 w = *(const s16x8*)(wimg + row * 64 + ((hi ^ r7) << 3));
        dA[mt] = __builtin_amdgcn_mfma_f32_16x16x32_bf16(w, bRA, zero, 0, 0, 0);
        dB[mt] = __builtin_amdgcn_mfma_f32_16x16x32_bf16(w, bRB, zero, 0, 0, 0);
    }
    #pragma unroll
    for (int mt = 0; mt < 4; ++mt) {
        int slot = mt * 2 + (hi >> 1);
        int off = ((slot ^ n7) << 4) + (hi & 1) * 8;
        uint2 vA = {cvt_pk(silu_f(dA[mt][0]), silu_f(dA[mt][1])),
                    cvt_pk(silu_f(dA[mt][2]), silu_f(dA[mt][3]))};
        *(uint2*)(bAq + n * 128 + off) = vA;
        uint2 vB = {cvt_pk(silu_f(dB[mt][0]), silu_f(dB[mt][1])),
                    cvt_pk(silu_f(dB[mt][2]), silu_f(dB[mt][3]))};
        *(uint2*)(bBq + n * 128 + off) = vB;
    }
    s16x8 b0A = *(const s16x8*)(bAq + n * 128 + ((hi ^ n7) << 4));
    s16x8 b1A = *(const s16x8*)(bAq + n * 128 + (((4 + hi) ^ n7) << 4));
    s16x8 b0B = *(const s16x8*)(bBq + n * 128 + ((hi ^ n7) << 4));
    s16x8 b1B = *(const s16x8*)(bBq + n * 128 + (((4 + hi) ^ n7) << 4));

    // L2, weights wimg[4096..8192)
    #pragma unroll
    for (int mt = 0; mt < 4; ++mt) {
        int row = mt * 16 + n, r7 = row & 7;
        s16x8 w0 = *(const s16x8*)(wimg + 4096 + row * 64 + ((hi ^ r7) << 3));
        s16x8 w1 = *(const s16x8*)(wimg + 4096 + row * 64 + (((4 + hi) ^ r7) << 3));
        dA[mt] = __builtin_amdgcn_mfma_f32_16x16x32_bf16(w0, b0A, zero, 0, 0, 0);
        dA[mt] = __builtin_amdgcn_mfma_f32_16x16x32_bf16(w1, b1A, dA[mt], 0, 0, 0);
        dB[mt] = __builtin_amdgcn_mfma_f32_16x16x32_bf16(w0, b0B, zero, 0, 0, 0);
        dB[mt] = __builtin_amdgcn_mfma_f32_16x16x32_bf16(w1, b1B, dB[mt], 0, 0, 0);
    }
    #pragma unroll
    for (int mt = 0; mt < 4; ++mt) {
        int slot = mt * 2 + (hi >> 1);
        int off = ((slot ^ n7) << 4) + (hi & 1) * 8;
        uint2 vA = {cvt_pk(silu_f(dA[mt][0]), silu_f(dA[mt][1])),
                    cvt_pk(silu_f(dA[mt][2]), silu_f(dA[mt][3]))};
        *(uint2*)(bAq + n * 128 + off) = vA;
        uint2 vB = {cvt_pk(silu_f(dB[mt][0]), silu_f(dB[mt][1])),
                    cvt_pk(silu_f(dB[mt][2]), silu_f(dB[mt][3]))};
        *(uint2*)(bBq + n * 128 + off) = vB;
    }
    b0A = *(const s16x8*)(bAq + n * 128 + ((hi ^ n7) << 4));
    b1A = *(const s16x8*)(bAq + n * 128 + (((4 + hi) ^ n7) << 4));
    b0B = *(const s16x8*)(bBq + n * 128 + ((hi ^ n7) << 4));
    b1B = *(const s16x8*)(bBq + n * 128 + (((4 + hi) ^ n7) << 4));

    // L3, weights wimg[8192..12288)
    #pragma unroll
    for (int mt = 0; mt < 4; ++mt) {
        int row = mt * 16 + n, r7 = row & 7;
        s16x8 w0 = *(const s16x8*)(wimg + 8192 + row * 64 + ((hi ^ r7) << 3));
        s16x8 w1 = *(const s16x8*)(wimg + 8192 + row * 64 + (((4 + hi) ^ r7) << 3));
        dA[mt] = __builtin_amdgcn_mfma_f32_16x16x32_bf16(w0, b0A, zero, 0, 0, 0);
        dA[mt] = __builtin_amdgcn_mfma_f32_16x16x32_bf16(w1, b1A, dA[mt], 0, 0, 0);
        dB[mt] = __builtin_amdgcn_mfma_f32_16x16x32_bf16(w0, b0B, zero, 0, 0, 0);
        dB[mt] = __builtin_amdgcn_mfma_f32_16x16x32_bf16(w1, b1B, dB[mt], 0, 0, 0);
    }
    #pragma unroll
    for (int mt = 0; mt < 4; ++mt) {
        int slot = mt * 2 + (hi >> 1);
        int off = ((slot ^ n7) << 4) + (hi & 1) * 8;
        uint2 vA = {cvt_pk(silu_f(dA[mt][0]), silu_f(dA[mt][1])),
                    cvt_pk(silu_f(dA[mt][2]), silu_f(dA[mt][3]))};
        *(uint2*)(bAq + n * 128 + off) = vA;
        uint2 vB = {cvt_pk(silu_f(dB[mt][0]), silu_f(dB[mt][1])),
                    cvt_pk(silu_f(dB[mt][2]), silu_f(dB[mt][3]))};
        *(uint2*)(bBq + n * 128 + off) = vB;
    }
    b0A = *(const s16x8*)(bAq + n * 128 + ((hi ^ n7) << 4));
    b1A = *(const s16x8*)(bAq + n * 128 + (((4 + hi) ^ n7) << 4));
    b0B = *(const s16x8*)(bBq + n * 128 + ((hi ^ n7) << 4));
    b1B = *(const s16x8*)(bBq + n * 128 + (((4 + hi) ^ n7) << 4));

    // L4: 128 outputs (l=0,1), weights wimg[12288..20480); contiguous stores.
    size_t rbA = (size_t)eA * 64, rbB = (size_t)eB * 64;
    const ushort* w4 = wimg + 12288;
    #pragma unroll
    for (int mt = 0; mt < 4; ++mt) {
        int row0 = mt * 16 + n, r70 = row0 & 7;
        int row1 = (mt + 4) * 16 + n, r71 = row1 & 7;
        s16x8 a0lo = *(const s16x8*)(w4 + row0 * 64 + ((hi ^ r70) << 3));
        s16x8 a1lo = *(const s16x8*)(w4 + row0 * 64 + (((4 + hi) ^ r70) << 3));
        s16x8 a0hi = *(const s16x8*)(w4 + row1 * 64 + ((hi ^ r71) << 3));
        s16x8 a1hi = *(const s16x8*)(w4 + row1 * 64 + (((4 + hi) ^ r71) << 3));
        f32x4 oloA = __builtin_amdgcn_mfma_f32_16x16x32_bf16(a0lo, b0A, zero, 0, 0, 0);
        oloA = __builtin_amdgcn_mfma_f32_16x16x32_bf16(a1lo, b1A, oloA, 0, 0, 0);
        f32x4 ohiA = __builtin_amdgcn_mfma_f32_16x16x32_bf16(a0hi, b0A, zero, 0, 0, 0);
        ohiA = __builtin_amdgcn_mfma_f32_16x16x32_bf16(a1hi, b1A, ohiA, 0, 0, 0);
        f32x4 oloB = __builtin_amdgcn_mfma_f32_16x16x32_bf16(a0lo, b0B, zero, 0, 0, 0);
        oloB = __builtin_amdgcn_mfma_f32_16x16x32_bf16(a1lo, b1B, oloB, 0, 0, 0);
        f32x4 ohiB = __builtin_amdgcn_mfma_f32_16x16x32_bf16(a0hi, b0B, zero, 0, 0, 0);
        ohiB = __builtin_amdgcn_mfma_f32_16x16x32_bf16(a1hi, b1B, ohiB, 0, 0, 0);
        if (okA) {
            uint4 val;
            val.x = cvt_pk(oloA[0], ohiA[0]);
            val.y = cvt_pk(oloA[1], ohiA[1]);
            val.z = cvt_pk(oloA[2], ohiA[2]);
            val.w = cvt_pk(oloA[3], ohiA[3]);
            *(uint4*)(tpw32 + rbA + mt * 16 + hi * 4) = val;
        }
        if (okB) {
            uint4 val;
            val.x = cvt_pk(oloB[0], ohiB[0]);
            val.y = cvt_pk(oloB[1], ohiB[1]);
            val.z = cvt_pk(oloB[2], ohiB[2]);
            val.w = cvt_pk(oloB[3], ohiB[3]);
            *(uint4*)(tpw32 + rbB + mt * 16 + hi * 4) = val;
        }
    }
}

// K6a: CSR aggregation. Wave per node, lane = channel. {eid,sender} in one
// coalesced int2 load; 4-edge batched loads hide gather latency.
__global__ __launch_bounds__(256) void agg_kernel(const float* __restrict__ angular,
                                                  const int2* __restrict__ csr_es,
                                                  const unsigned* __restrict__ tpw32,
                                                  const int* __restrict__ offsets,
                                                  const ushort* __restrict__ x_ws,
                                                  ushort* __restrict__ agg, int N) {
    int wave = threadIdx.x >> 6, lane = threadIdx.x & 63;
    int node = blockIdx.x * 4 + wave;
    if (node >= N) return;
    int beg = offsets[node], end = offsets[node + 1];
    float a0 = 0, a1 = 0, a2 = 0, a3 = 0;
    for (int cb = beg; cb < end; cb += 64) {
        int m = min(64, end - cb);
        int2 es = csr_es[cb + min(lane, m - 1)];
        int ev = es.x, sv = es.y;
        for (int e0 = 0; e0 < m; e0 += 4) {
            unsigned t[4];
            ushort x[4];
            float4 g[4];
            #pragma unroll
            for (int j = 0; j < 4; ++j) {
                int e = e0 + j;
                int ec = min(e, m - 1);
                int eidj = __shfl(ev, ec);
                t[j] = tpw32[(size_t)eidj * 64 + lane];
                x[j] = x_ws[(size_t)__shfl(sv, ec) * 64 + lane];
                if (e < m) g[j] = *(const float4*)(angular + (size_t)eidj * 16);
                else g[j] = make_float4(0.f, 0.f, 0.f, 0.f);
            }
            #pragma unroll
            for (int j = 0; j < 4; ++j) {
                float xv = bf2f(x[j]);
                float tp0 = u2f(t[j] << 16);
                float tp1 = u2f(t[j] & 0xffff0000u);
                float y0 = xv * tp0, y1 = xv * tp1;
                a0 += g[j].x * y0;
                a1 += g[j].y * y1;
                a2 += g[j].z * y1;
                a3 += g[j].w * y1;
            }
        }
    }
    size_t b = (size_t)node * 256 + lane;
    agg[b] = f2bf(a0 * 0.1f);
    agg[b + 64] = f2bf(a1 * 0.1f);
    agg[b + 128] = f2bf(a2 * 0.1f);
    agg[b + 192] = f2bf(a3 * 0.1f);
}

// K6b: per-32-node tile: feats = agg@W_lin (MFMA), scale by wn, out = f@W_p (+sc0).
__global__ __launch_bounds__(256) void node_out2_kernel(
    const float* __restrict__ nf, const float* __restrict__ one_hot,
    const ushort* __restrict__ wimg, const float* __restrict__ W_c0,
    const float* __restrict__ W_c1, const ushort* __restrict__ agg,
    float* __restrict__ out) {
    __shared__ __align__(16) ushort sWl[2 * 64 * 72];
    __shared__ __align__(16) ushort sF[4][32 * 72];
    __shared__ float sSc[32][64];
    __shared__ float sWc[2][640];
    __shared__ int sElem[32];
    int tid = threadIdx.x;
    int n0 = blockIdx.x * 32;
    int lane = tid & 63, m = tid >> 6;
    int lsel = (m == 0) ? 0 : 1;

    // direct-from-global W_p B-fragments (L2-resident image)
    s16x8 pf[4][2];
    #pragma unroll
    for (int nt = 0; nt < 4; ++nt)
        #pragma unroll
        for (int ks = 0; ks < 2; ++ks)
            pf[nt][ks] = *(const s16x8*)(wimg + 29696 +
                (lsel * 64 + nt * 16 + (lane & 15)) * 72 + ks * 32 + (lane >> 4) * 8);

    for (int i = tid; i < 1152; i += 256)
        ((s16x8*)sWl)[i] = ((const s16x8*)(wimg + 20480))[i];
    for (int i = tid; i < 1280; i += 256)
        sWc[i >= 640][i % 640] = (i >= 640 ? W_c1 : W_c0)[i % 640];
    if (tid < 32) {
        int nn = n0 + tid, e = 0;
        for (int a = 0; a < 10; ++a)
            if (one_hot[(size_t)nn * 10 + a] > 0.5f) { e = a; break; }
        sElem[tid] = e;
    }
    __syncthreads();

    // sc0 skip connection: 8 threads per node, 8 k's per thread, bf16 W_skip
    {
        int nl = tid >> 3, k0 = (tid & 7) * 8;
        int nn = n0 + nl, elem = sElem[nl];
        float acc[8] = {0, 0, 0, 0, 0, 0, 0, 0};
        const ushort* wskb = wimg + 38912;
        for (int c = 0; c < 64; ++c) {
            float v = nf[(size_t)nn * 64 + c];
            s16x8 w = *(const s16x8*)(wskb + ((size_t)c * 10 + elem) * 64 + k0);
            #pragma unroll
            for (int j = 0; j < 8; ++j) acc[j] += v * bf2f((ushort)w[j]);
        }
        #pragma unroll
        for (int j = 0; j < 8; ++j) sSc[nl][k0 + j] = acc[j];
    }

    // GEMM1: feats[m] = agg[:,m,:] @ W_lin[lsel]   (M=32, K=64, N=64)
    f32x4 acc[2][4] = {};
    s16x8 afr[2][2];
    #pragma unroll
    for (int mt = 0; mt < 2; ++mt)
        #pragma unroll
        for (int ks = 0; ks < 2; ++ks)
            afr[mt][ks] = *(const s16x8*)(agg +
                (((size_t)(n0 + mt * 16 + (lane & 15))) * 4 + m) * 64 +
                ks * 32 + (lane >> 4) * 8);
    #pragma unroll
    for (int nt = 0; nt < 4; ++nt)
        #pragma unroll
        for (int ks = 0; ks < 2; ++ks) {
            s16x8 b = *(const s16x8*)(sWl + (lsel * 64 + nt * 16 + (lane & 15)) * 72 +
                                      ks * 32 + (lane >> 4) * 8);
            #pragma unroll
            for (int mt = 0; mt < 2; ++mt)
                acc[mt][nt] = __builtin_amdgcn_mfma_f32_16x16x32_bf16(afr[mt][ks], b,
                                                                      acc[mt][nt], 0, 0, 0);
        }

    // scale by wn and write bf16 to sF
    #pragma unroll
    for (int mt = 0; mt < 2; ++mt)
        #pragma unroll
        for (int nt = 0; nt < 4; ++nt)
            #pragma unroll
            for (int r = 0; r < 4; ++r) {
                int nl = mt * 16 + (lane >> 4) * 4 + r;
                int k = nt * 16 + (lane & 15);
                float scale = sWc[lsel][sElem[nl] * 64 + k];
                sF[m][nl * 72 + k] = f2bf(acc[mt][nt][r] * scale);
            }
    __syncthreads();

    // GEMM2: out_m = f[m] @ W_p{0|1}
    f32x4 acc2[2][4] = {};
    s16x8 af2[2][2];
    #pragma unroll
    for (int mt = 0; mt < 2; ++mt)
        #pragma unroll
        for (int ks = 0; ks < 2; ++ks)
            af2[mt][ks] = *(const s16x8*)(&sF[m][(mt * 16 + (lane & 15)) * 72 +
                                                 ks * 32 + (lane >> 4) * 8]);
    #pragma unroll
    for (int nt = 0; nt < 4; ++nt)
        #pragma unroll
        for (int ks = 0; ks < 2; ++ks) {
            #pragma unroll
            for (int mt = 0; mt < 2; ++mt)
                acc2[mt][nt] = __builtin_amdgcn_mfma_f32_16x16x32_bf16(af2[mt][ks],
                                                                       pf[nt][ks],
                                                                       acc2[mt][nt], 0, 0, 0);
        }

    // epilogue
    #pragma unroll
    for (int mt = 0; mt < 2; ++mt)
        #pragma unroll
        for (int nt = 0; nt < 4; ++nt)
            #pragma unroll
            for (int r = 0; r < 4; ++r) {
                int nl = mt * 16 + (lane >> 4) * 4 + r;
                int k = nt * 16 + (lane & 15);
                size_t nn = (size_t)n0 + nl;
                if (m == 0)
                    out[nn * 256 + k] = acc2[mt][nt][r] + sSc[nl][k];
                else
                    out[nn * 256 + 64 + k * 3 + (m - 1)] = acc2[mt][nt][r];
            }
}

extern "C" void kernel_launch(void* const* d_in, const int* in_sizes, int n_in,
                              void* d_out, int out_size, void* d_ws, size_t ws_size,
                              hipStream_t stream) {
    const float* node_features = (const float*)d_in[0];
    const float* one_hot = (const float*)d_in[1];
    const float* angular = (const float*)d_in[2];
    const float* radial = (const float*)d_in[3];
    const float* W_up = (const float*)d_in[4];
    const float* W_mlp1 = (const float*)d_in[5];
    const float* W_mlp2 = (const float*)d_in[6];
    const float* W_mlp3 = (const float*)d_in[7];
    const float* W_mlp4 = (const float*)d_in[8];
    const float* W_lin = (const float*)d_in[9];
    const float* W_skip = (const float*)d_in[10];
    const float* W_c0 = (const float*)d_in[11];
    const float* W_c1 = (const float*)d_in[12];
    const float* W_p0 = (const float*)d_in[13];
    const float* W_p1 = (const float*)d_in[14];
    const int* edge_index = (const int*)d_in[15];
    float* out = (float*)d_out;

    int N = in_sizes[0] / 64;
    int E = in_sizes[2] / 16;
    const int* sender = edge_index;
    const int* receiver = edge_index + E;

    char* p = (char*)d_ws;
    ushort* x_ws = (ushort*)p;      p += (size_t)N * 64 * 2;
    unsigned* tpw32 = (unsigned*)p; p += (size_t)E * 64 * 4;
    ushort* agg = (ushort*)p;       p += (size_t)N * 256 * 2;
    ushort* wimg = (ushort*)p;      p += 79872 * 2;
    int* counts = (int*)p;          p += (size_t)N * 4;
    int* offsets = (int*)p;         p += (size_t)(N + 1) * 4;
    int* rank = (int*)p;            p += (size_t)E * 4;
    int2* csr_es = (int2*)p;        p += (size_t)E * 8;

    prep_up_kernel<<<N / 32 + 312, 256, 0, stream>>>(node_features, W_up, x_ws,
                                                     W_mlp1, W_mlp2, W_mlp3, W_mlp4,
                                                     W_lin, W_p0, W_p1, W_skip, wimg,
                                                     counts, N);
    hist_kernel<<<(E + 255) / 256, 256, 0, stream>>>(receiver, counts, rank, E);
    scan_kernel<<<1, 1024, 0, stream>>>(counts, offsets, N);
    edge_mlp_kernel<<<(E + 127) / 128, 256, 0, stream>>>(receiver, sender, rank,
                                                         offsets, radial, csr_es,
                                                         wimg, tpw32, E);
    agg_kernel<<<(N + 3) / 4, 256, 0, stream>>>(angular, csr_es, tpw32,
                                                offsets, x_ws, agg, N);
    node_out2_kernel<<<N / 32, 256, 0, stream>>>(node_features, one_hot, wimg,
                                                 W_c0, W_c1, agg, out);
}